// Round 1
// baseline (563.456 us; speedup 1.0000x reference)
//
#include <hip/hip_runtime.h>
#include <cstdint>
#include <cstddef>

typedef unsigned short u16;
typedef __bf16 bf16x8 __attribute__((ext_vector_type(8)));
typedef float f32x4 __attribute__((ext_vector_type(4)));
typedef u16 u16x8 __attribute__((ext_vector_type(8)));
typedef u16 u16x4 __attribute__((ext_vector_type(4)));

#define NB 4
#define NN 4096
#define ND 1024
#define NH 16
#define NTOK (NB * NN)   // 16384

__device__ __forceinline__ u16 f2bf(float f) {
    unsigned u = __float_as_uint(f);
    u += 0x7fffu + ((u >> 16) & 1u);
    return (u16)(u >> 16);
}

__device__ __forceinline__ void gload_lds16(const void* g, void* l) {
    __builtin_amdgcn_global_load_lds(
        (const __attribute__((address_space(1))) void*)g,
        (__attribute__((address_space(3))) void*)l, 16, 0, 0);
}

// ---------------------------------------------------------------------------
// prep: cast x (fp32->bf16) and Wq|Wk|Wv|Wo into one bf16 weight block
// ---------------------------------------------------------------------------
__global__ __launch_bounds__(256) void prep_cast(
    const float* __restrict__ x,
    const float* __restrict__ wq, const float* __restrict__ wk,
    const float* __restrict__ wv, const float* __restrict__ wo,
    u16* __restrict__ xb, u16* __restrict__ wb)
{
    const int n_x4 = (NTOK * ND) / 4;       // 4194304
    const int n_w4 = (ND * ND) / 4;         // 262144 per weight
    const int total = n_x4 + 4 * n_w4;      // 5242880
    for (int i = blockIdx.x * blockDim.x + threadIdx.x; i < total;
         i += gridDim.x * blockDim.x) {
        float4 v;
        u16* dst;
        if (i < n_x4) {
            v = ((const float4*)x)[i];
            dst = xb + (size_t)i * 4;
        } else {
            int j = i - n_x4;
            int w = j / n_w4;
            int off = j - w * n_w4;
            const float* src = (w == 0) ? wq : (w == 1) ? wk : (w == 2) ? wv : wo;
            v = ((const float4*)src)[off];
            dst = wb + (size_t)j * 4;
        }
        u16x4 o;
        o[0] = f2bf(v.x); o[1] = f2bf(v.y); o[2] = f2bf(v.z); o[3] = f2bf(v.w);
        *(u16x4*)dst = o;
    }
}

// ---------------------------------------------------------------------------
// gemm_bt: C[m][n] = sum_k A[m][k]*B[n][k]  (both row-major along k), bf16 MFMA
// 128x128 tile, BK=32, 256 threads = 4 waves (2x2 of 64x64)
// OUT_MODE 0: bf16 store; OUT_MODE 1: f32 store + bias[col] + resid[m][col]
// ---------------------------------------------------------------------------
template <int OUT_MODE>
__global__ __launch_bounds__(256, 2) void gemm_bt(
    const u16* __restrict__ A, int lda,
    const u16* __restrict__ Bw, int ldb,
    void* __restrict__ Cout, int ldc, int K,
    const float* __restrict__ bias, const float* __restrict__ resid,
    int rows_per_batch, size_t b_stride)
{
    __shared__ alignas(16) u16 lA[128 * 32];
    __shared__ alignas(16) u16 lB[128 * 32];

    const int tid = threadIdx.x;
    const int wv = tid >> 6, lane = tid & 63;
    const int quad = lane >> 4, lrow = lane & 15;
    const int row0 = blockIdx.y * 128, col0 = blockIdx.x * 128;
    const int wm = (wv >> 1) * 64, wn = (wv & 1) * 64;

    const u16* Bp = Bw + (b_stride ? (size_t)(row0 / rows_per_batch) * b_stride : 0);

    f32x4 acc[4][4] = {};

    const int srow = lane >> 2;          // 0..15 within chunk
    const int scolh = (lane & 3) * 8;    // halfword col in k

    for (int k0 = 0; k0 < K; k0 += 32) {
        __syncthreads();
        const int c0 = wv * 2;
#pragma unroll
        for (int c = c0; c < c0 + 2; ++c) {
            int row = c * 16 + srow;
            gload_lds16(A + (size_t)(row0 + row) * lda + k0 + scolh, &lA[c * 512]);
            gload_lds16(Bp + (size_t)(col0 + row) * ldb + k0 + scolh, &lB[c * 512]);
        }
        __syncthreads();

        bf16x8 af[4], bfv[4];
#pragma unroll
        for (int t = 0; t < 4; ++t)
            af[t] = *(const bf16x8*)&lA[(wm + t * 16 + lrow) * 32 + quad * 8];
#pragma unroll
        for (int t = 0; t < 4; ++t)
            bfv[t] = *(const bf16x8*)&lB[(wn + t * 16 + lrow) * 32 + quad * 8];

#pragma unroll
        for (int mt = 0; mt < 4; ++mt)
#pragma unroll
            for (int nt = 0; nt < 4; ++nt)
                acc[mt][nt] = __builtin_amdgcn_mfma_f32_16x16x32_bf16(
                    af[mt], bfv[nt], acc[mt][nt], 0, 0, 0);
    }

    // epilogue; C/D layout: col = lane&15, row = quad*4 + reg
#pragma unroll
    for (int mt = 0; mt < 4; ++mt)
#pragma unroll
        for (int nt = 0; nt < 4; ++nt)
#pragma unroll
            for (int r = 0; r < 4; ++r) {
                int grow = row0 + wm + mt * 16 + quad * 4 + r;
                int gcol = col0 + wn + nt * 16 + lrow;
                if (OUT_MODE == 0) {
                    ((u16*)Cout)[(size_t)grow * ldc + gcol] = f2bf(acc[mt][nt][r]);
                } else {
                    float vv = acc[mt][nt][r] + bias[gcol] +
                               resid[(size_t)grow * ldc + gcol];
                    ((float*)Cout)[(size_t)grow * ldc + gcol] = vv;
                }
            }
}

// ---------------------------------------------------------------------------
// stage2: per (b,h): kk=K^T K, ktv=K^T V (MFMA w/ LDS transpose), +alpha*I,
// Gauss-Jordan solve on [kk|ktv], column softmax, M = Wo_h @ attn^T (MFMA)
// grid = 64 workgroups (b*16+h), 256 threads
// ---------------------------------------------------------------------------
__global__ __launch_bounds__(256, 1) void stage2_kernel(
    const u16* __restrict__ qkv,   // [16384][3072] bf16 (q|k|v)
    const u16* __restrict__ wb,    // [4096][1024] bf16, Wo rows at 3072
    const float* __restrict__ alpha,
    const float* __restrict__ temp,
    u16* __restrict__ Mout)        // [4][1024][1024] bf16
{
    __shared__ alignas(16) u16 sKt[4][64][40];   // per-wave K^T tile (pad 40)
    __shared__ alignas(16) u16 sVt[4][64][40];
    __shared__ float S[64][133];                 // augmented [kk | ktv]
    __shared__ alignas(16) u16 sAttn[64][72];    // attn bf16 (pad 72 -> 144B rows)

    const int tid = threadIdx.x;
    const int wv = tid >> 6, lane = tid & 63;
    const int quad = lane >> 4, lrow = lane & 15;
    const int b = blockIdx.x >> 4, h = blockIdx.x & 15;

    // ---- Phase A: kk/ktv partials per wave (each wave: 1024 n-values) ----
    f32x4 akk[4][4] = {};
    f32x4 aktv[4][4] = {};
    const u16* kbase = qkv + ND + h * 64;        // k slice
    const u16* vbase = qkv + 2 * ND + h * 64;    // v slice
    const size_t tok0 = (size_t)b * NN;

    for (int it = 0; it < 32; ++it) {
        const int n0 = wv * 1024 + it * 32;
        // transpose-stage 32 n-rows x 64 d into sKt/sVt (wave-private)
#pragma unroll
        for (int pass = 0; pass < 4; ++pass) {
            int nl = pass * 8 + (lane >> 3);
            int d0 = (lane & 7) * 8;
            size_t roff = (tok0 + n0 + nl) * 3072 + d0;
            u16x8 kvv = *(const u16x8*)(kbase + roff);
            u16x8 vvv = *(const u16x8*)(vbase + roff);
#pragma unroll
            for (int j = 0; j < 8; ++j) {
                sKt[wv][d0 + j][nl] = kvv[j];
                sVt[wv][d0 + j][nl] = vvv[j];
            }
        }
        // same-wave LDS: in-order pipe makes writes visible to later reads
        bf16x8 fK[4], fV[4];
#pragma unroll
        for (int t = 0; t < 4; ++t) {
            fK[t] = *(const bf16x8*)&sKt[wv][t * 16 + lrow][quad * 8];
            fV[t] = *(const bf16x8*)&sVt[wv][t * 16 + lrow][quad * 8];
        }
#pragma unroll
        for (int mt = 0; mt < 4; ++mt)
#pragma unroll
            for (int et = 0; et < 4; ++et) {
                akk[mt][et] = __builtin_amdgcn_mfma_f32_16x16x32_bf16(
                    fK[mt], fK[et], akk[mt][et], 0, 0, 0);
                aktv[mt][et] = __builtin_amdgcn_mfma_f32_16x16x32_bf16(
                    fK[mt], fV[et], aktv[mt][et], 0, 0, 0);
            }
    }

    // ---- Phase B: cross-wave reduce into S ----
    for (int w = 0; w < 4; ++w) {
        if (wv == w) {
#pragma unroll
            for (int mt = 0; mt < 4; ++mt)
#pragma unroll
                for (int et = 0; et < 4; ++et)
#pragma unroll
                    for (int r = 0; r < 4; ++r) {
                        int row = mt * 16 + quad * 4 + r;
                        int col = et * 16 + lrow;
                        if (w == 0) {
                            S[row][col] = akk[mt][et][r];
                            S[row][64 + col] = aktv[mt][et][r];
                        } else {
                            S[row][col] += akk[mt][et][r];
                            S[row][64 + col] += aktv[mt][et][r];
                        }
                    }
        }
        __syncthreads();
    }
    if (tid < 64) S[tid][tid] += alpha[0];
    __syncthreads();

    // ---- Phase C: Gauss-Jordan (no pivoting; kk is SPD diag-dominant) ----
    {
        const int r = tid & 63, cg = tid >> 6;
        for (int p = 0; p < 64; ++p) {
            float pv = S[p][p];
            float f = S[r][p];
            __syncthreads();
            if (r != p) {
                float fp = f / pv;
                int cbase = cg * 32;
#pragma unroll
                for (int cc = 0; cc < 32; ++cc) {
                    int c = cbase + cc;
                    if (c > p) S[r][c] -= fp * S[p][c];
                }
            }
            __syncthreads();
        }
    }

    // ---- Phase D: X = S[:,64:]/diag; column softmax over rows; bf16 attn ----
    if (tid < 64) {
        const int e = tid;
        const float invT = 1.0f / temp[0];
        float mx = -1e30f;
        for (int d = 0; d < 64; ++d) {
            float xv = (S[d][64 + e] / S[d][d]) * invT;
            S[d][64 + e] = xv;
            mx = fmaxf(mx, xv);
        }
        float sum = 0.f;
        for (int d = 0; d < 64; ++d) {
            float ev = __expf(S[d][64 + e] - mx);
            S[d][64 + e] = ev;
            sum += ev;
        }
        float rs = 1.0f / sum;
        for (int d = 0; d < 64; ++d) sAttn[d][e] = f2bf(S[d][64 + e] * rs);
    }
    __syncthreads();

    // ---- Phase E: M_b[o][h*64+d] = sum_e Wo[o][h*64+e]*attn[d][e] via MFMA ----
    {
        bf16x8 fB[4][2];
#pragma unroll
        for (int nt = 0; nt < 4; ++nt)
#pragma unroll
            for (int ks = 0; ks < 2; ++ks)
                fB[nt][ks] = *(const bf16x8*)&sAttn[nt * 16 + lrow][ks * 32 + quad * 8];

        const u16* wo = wb + (size_t)3072 * ND + h * 64;
        u16* Mb = Mout + (size_t)b * ND * ND + h * 64;
        for (int i = 0; i < 16; ++i) {
            int mt = wv * 16 + i;
            int oA = mt * 16 + lrow;
            bf16x8 fA[2];
#pragma unroll
            for (int ks = 0; ks < 2; ++ks)
                fA[ks] = *(const bf16x8*)(wo + (size_t)oA * ND + ks * 32 + quad * 8);
#pragma unroll
            for (int nt = 0; nt < 4; ++nt) {
                f32x4 acc = {};
                acc = __builtin_amdgcn_mfma_f32_16x16x32_bf16(fA[0], fB[nt][0], acc, 0, 0, 0);
                acc = __builtin_amdgcn_mfma_f32_16x16x32_bf16(fA[1], fB[nt][1], acc, 0, 0, 0);
#pragma unroll
                for (int r = 0; r < 4; ++r) {
                    int o = mt * 16 + quad * 4 + r;
                    Mb[(size_t)o * ND + nt * 16 + lrow] = f2bf(acc[r]);
                }
            }
        }
    }
}

// ---------------------------------------------------------------------------
// layernorm: one block per row of 1024
// ---------------------------------------------------------------------------
__global__ __launch_bounds__(256) void ln_kernel(
    const float* __restrict__ y, const float* __restrict__ gamma,
    const float* __restrict__ beta, float* __restrict__ out)
{
    const int row = blockIdx.x, tid = threadIdx.x;
    const float4 v = ((const float4*)(y + (size_t)row * ND))[tid];
    float s = v.x + v.y + v.z + v.w;
    float q = v.x * v.x + v.y * v.y + v.z * v.z + v.w * v.w;
#pragma unroll
    for (int off = 32; off > 0; off >>= 1) {
        s += __shfl_xor(s, off, 64);
        q += __shfl_xor(q, off, 64);
    }
    __shared__ float ss[4], sq[4];
    const int wv = tid >> 6;
    if ((tid & 63) == 0) { ss[wv] = s; sq[wv] = q; }
    __syncthreads();
    s = ss[0] + ss[1] + ss[2] + ss[3];
    q = sq[0] + sq[1] + sq[2] + sq[3];
    const float mu = s * (1.0f / ND);
    const float var = q * (1.0f / ND) - mu * mu;
    const float rs = rsqrtf(var + 1e-5f);
    const float4 g = ((const float4*)gamma)[tid];
    const float4 bt = ((const float4*)beta)[tid];
    float4 o;
    o.x = (v.x - mu) * rs * g.x + bt.x;
    o.y = (v.y - mu) * rs * g.y + bt.y;
    o.z = (v.z - mu) * rs * g.z + bt.z;
    o.w = (v.w - mu) * rs * g.w + bt.w;
    ((float4*)(out + (size_t)row * ND))[tid] = o;
}

// ---------------------------------------------------------------------------
extern "C" void kernel_launch(void* const* d_in, const int* in_sizes, int n_in,
                              void* d_out, int out_size, void* d_ws, size_t ws_size,
                              hipStream_t stream)
{
    const float* x     = (const float*)d_in[0];
    const float* Wq    = (const float*)d_in[1];
    const float* Wk    = (const float*)d_in[2];
    const float* Wv    = (const float*)d_in[3];
    const float* Wo    = (const float*)d_in[4];
    const float* bo    = (const float*)d_in[5];
    const float* alpha = (const float*)d_in[6];
    const float* temp  = (const float*)d_in[7];
    const float* gamma = (const float*)d_in[8];
    const float* beta  = (const float*)d_in[9];

    char* ws = (char*)d_ws;
    u16* xb   = (u16*)(ws);                         // 33,554,432 B
    u16* wb   = (u16*)(ws + 33554432);              //  8,388,608 B
    u16* qkv  = (u16*)(ws + 41943040);              // 100,663,296 B
    u16* Mb   = (u16*)(ws + 142606336);             //  8,388,608 B
    float* y  = (float*)(ws + 150994944);           // 67,108,864 B  (total 208 MB)
    float* out = (float*)d_out;

    prep_cast<<<dim3(4096), dim3(256), 0, stream>>>(x, Wq, Wk, Wv, Wo, xb, wb);

    // QKV: [16384 x 3072] = x_bf16 @ [Wq;Wk;Wv]^T
    gemm_bt<0><<<dim3(24, 128), dim3(256), 0, stream>>>(
        xb, 1024, wb, 1024, (void*)qkv, 3072, 1024,
        nullptr, nullptr, 1 << 30, (size_t)0);

    stage2_kernel<<<dim3(64), dim3(256), 0, stream>>>(qkv, wb, alpha, temp, Mb);

    // y = q @ M_b^T + bo + x   (per-batch weights)
    gemm_bt<1><<<dim3(8, 128), dim3(256), 0, stream>>>(
        qkv, 3072, Mb, 1024, (void*)y, 1024, 1024,
        bo, x, 4096, (size_t)(1024 * 1024));

    ln_kernel<<<dim3(16384), dim3(256), 0, stream>>>(y, gamma, beta, out);
}

// Round 2
// 533.245 us; speedup vs baseline: 1.0567x; 1.0567x over previous
//
#include <hip/hip_runtime.h>
#include <cstdint>
#include <cstddef>

typedef unsigned short u16;
typedef __bf16 bf16x8 __attribute__((ext_vector_type(8)));
typedef float f32x4 __attribute__((ext_vector_type(4)));
typedef u16 u16x8 __attribute__((ext_vector_type(8)));
typedef u16 u16x4 __attribute__((ext_vector_type(4)));

#define NB 4
#define NN 4096
#define ND 1024
#define NH 16
#define NTOK (NB * NN)   // 16384

__device__ __forceinline__ u16 f2bf(float f) {
    unsigned u = __float_as_uint(f);
    u += 0x7fffu + ((u >> 16) & 1u);
    return (u16)(u >> 16);
}

__device__ __forceinline__ void gload_lds16(const void* g, void* l) {
    __builtin_amdgcn_global_load_lds(
        (const __attribute__((address_space(1))) void*)g,
        (__attribute__((address_space(3))) void*)l, 16, 0, 0);
}

// ---------------------------------------------------------------------------
// prep: cast x (fp32->bf16) and Wq|Wk|Wv|Wo into one bf16 weight block
// ---------------------------------------------------------------------------
__global__ __launch_bounds__(256) void prep_cast(
    const float* __restrict__ x,
    const float* __restrict__ wq, const float* __restrict__ wk,
    const float* __restrict__ wv, const float* __restrict__ wo,
    u16* __restrict__ xb, u16* __restrict__ wb)
{
    const int n_x4 = (NTOK * ND) / 4;       // 4194304
    const int n_w4 = (ND * ND) / 4;         // 262144 per weight
    const int total = n_x4 + 4 * n_w4;      // 5242880
    for (int i = blockIdx.x * blockDim.x + threadIdx.x; i < total;
         i += gridDim.x * blockDim.x) {
        float4 v;
        u16* dst;
        if (i < n_x4) {
            v = ((const float4*)x)[i];
            dst = xb + (size_t)i * 4;
        } else {
            int j = i - n_x4;
            int w = j / n_w4;
            int off = j - w * n_w4;
            const float* src = (w == 0) ? wq : (w == 1) ? wk : (w == 2) ? wv : wo;
            v = ((const float4*)src)[off];
            dst = wb + (size_t)j * 4;
        }
        u16x4 o;
        o[0] = f2bf(v.x); o[1] = f2bf(v.y); o[2] = f2bf(v.z); o[3] = f2bf(v.w);
        *(u16x4*)dst = o;
    }
}

// ---------------------------------------------------------------------------
// gemm_bt: C[m][n] = sum_k A[m][k]*B[n][k]  (both row-major along k), bf16 MFMA
// 128x128 tile, BK=32, 256 threads = 4 waves (2x2 of 64x64)
// OUT_MODE 0: bf16 store; OUT_MODE 1: f32 store + bias[col] + resid[m][col]
// ---------------------------------------------------------------------------
template <int OUT_MODE>
__global__ __launch_bounds__(256, 2) void gemm_bt(
    const u16* __restrict__ A, int lda,
    const u16* __restrict__ Bw, int ldb,
    void* __restrict__ Cout, int ldc, int K,
    const float* __restrict__ bias, const float* __restrict__ resid,
    int rows_per_batch, size_t b_stride)
{
    __shared__ alignas(16) u16 lA[128 * 32];
    __shared__ alignas(16) u16 lB[128 * 32];

    const int tid = threadIdx.x;
    const int wv = tid >> 6, lane = tid & 63;
    const int quad = lane >> 4, lrow = lane & 15;
    const int row0 = blockIdx.y * 128, col0 = blockIdx.x * 128;
    const int wm = (wv >> 1) * 64, wn = (wv & 1) * 64;

    const u16* Bp = Bw + (b_stride ? (size_t)(row0 / rows_per_batch) * b_stride : 0);

    f32x4 acc[4][4] = {};

    const int srow = lane >> 2;          // 0..15 within chunk
    const int scolh = (lane & 3) * 8;    // halfword col in k

    for (int k0 = 0; k0 < K; k0 += 32) {
        __syncthreads();
        const int c0 = wv * 2;
#pragma unroll
        for (int c = c0; c < c0 + 2; ++c) {
            int row = c * 16 + srow;
            gload_lds16(A + (size_t)(row0 + row) * lda + k0 + scolh, &lA[c * 512]);
            gload_lds16(Bp + (size_t)(col0 + row) * ldb + k0 + scolh, &lB[c * 512]);
        }
        __syncthreads();

        bf16x8 af[4], bfv[4];
#pragma unroll
        for (int t = 0; t < 4; ++t)
            af[t] = *(const bf16x8*)&lA[(wm + t * 16 + lrow) * 32 + quad * 8];
#pragma unroll
        for (int t = 0; t < 4; ++t)
            bfv[t] = *(const bf16x8*)&lB[(wn + t * 16 + lrow) * 32 + quad * 8];

#pragma unroll
        for (int mt = 0; mt < 4; ++mt)
#pragma unroll
            for (int nt = 0; nt < 4; ++nt)
                acc[mt][nt] = __builtin_amdgcn_mfma_f32_16x16x32_bf16(
                    af[mt], bfv[nt], acc[mt][nt], 0, 0, 0);
    }

    // epilogue; C/D layout: col = lane&15, row = quad*4 + reg
#pragma unroll
    for (int mt = 0; mt < 4; ++mt)
#pragma unroll
        for (int nt = 0; nt < 4; ++nt)
#pragma unroll
            for (int r = 0; r < 4; ++r) {
                int grow = row0 + wm + mt * 16 + quad * 4 + r;
                int gcol = col0 + wn + nt * 16 + lrow;
                if (OUT_MODE == 0) {
                    ((u16*)Cout)[(size_t)grow * ldc + gcol] = f2bf(acc[mt][nt][r]);
                } else {
                    float vv = acc[mt][nt][r] + bias[gcol] +
                               resid[(size_t)grow * ldc + gcol];
                    ((float*)Cout)[(size_t)grow * ldc + gcol] = vv;
                }
            }
}

// ---------------------------------------------------------------------------
// stage2a: partial kk/ktv per (b,h,split). grid = (64, 16), 256 threads.
// Each block covers 256 tokens; each wave 64 tokens (2 iters of 32).
// Writes fp32 partial tile [64][128] (kk | ktv) to Part[bh*16+split].
// ---------------------------------------------------------------------------
__global__ __launch_bounds__(256) void stage2a_kernel(
    const u16* __restrict__ qkv,   // [16384][3072] bf16 (q|k|v)
    float* __restrict__ Part)      // [64*16][64*128] fp32
{
    __shared__ alignas(16) u16 sKt[4][64][40];   // per-wave K^T tile (pad 40)
    __shared__ alignas(16) u16 sVt[4][64][40];
    __shared__ float S[64][132];

    const int tid = threadIdx.x;
    const int wv = tid >> 6, lane = tid & 63;
    const int quad = lane >> 4, lrow = lane & 15;
    const int bh = blockIdx.x, split = blockIdx.y;
    const int b = bh >> 4, h = bh & 15;

    f32x4 akk[4][4] = {};
    f32x4 aktv[4][4] = {};
    const u16* kbase = qkv + ND + h * 64;
    const u16* vbase = qkv + 2 * ND + h * 64;
    const size_t tok0 = (size_t)b * NN;

    for (int it = 0; it < 2; ++it) {
        const int n0 = split * 256 + wv * 64 + it * 32;
#pragma unroll
        for (int pass = 0; pass < 4; ++pass) {
            int nl = pass * 8 + (lane >> 3);
            int d0 = (lane & 7) * 8;
            size_t roff = (tok0 + n0 + nl) * 3072 + d0;
            u16x8 kvv = *(const u16x8*)(kbase + roff);
            u16x8 vvv = *(const u16x8*)(vbase + roff);
#pragma unroll
            for (int j = 0; j < 8; ++j) {
                sKt[wv][d0 + j][nl] = kvv[j];
                sVt[wv][d0 + j][nl] = vvv[j];
            }
        }
        bf16x8 fK[4], fV[4];
#pragma unroll
        for (int t = 0; t < 4; ++t) {
            fK[t] = *(const bf16x8*)&sKt[wv][t * 16 + lrow][quad * 8];
            fV[t] = *(const bf16x8*)&sVt[wv][t * 16 + lrow][quad * 8];
        }
#pragma unroll
        for (int mt = 0; mt < 4; ++mt)
#pragma unroll
            for (int et = 0; et < 4; ++et) {
                akk[mt][et] = __builtin_amdgcn_mfma_f32_16x16x32_bf16(
                    fK[mt], fK[et], akk[mt][et], 0, 0, 0);
                aktv[mt][et] = __builtin_amdgcn_mfma_f32_16x16x32_bf16(
                    fK[mt], fV[et], aktv[mt][et], 0, 0, 0);
            }
    }

    // cross-wave reduce into S
    for (int w = 0; w < 4; ++w) {
        if (wv == w) {
#pragma unroll
            for (int mt = 0; mt < 4; ++mt)
#pragma unroll
                for (int et = 0; et < 4; ++et)
#pragma unroll
                    for (int r = 0; r < 4; ++r) {
                        int row = mt * 16 + quad * 4 + r;
                        int col = et * 16 + lrow;
                        if (w == 0) {
                            S[row][col] = akk[mt][et][r];
                            S[row][64 + col] = aktv[mt][et][r];
                        } else {
                            S[row][col] += akk[mt][et][r];
                            S[row][64 + col] += aktv[mt][et][r];
                        }
                    }
        }
        __syncthreads();
    }

    // coalesced fp32 write-out
    float* dst = Part + (size_t)(bh * 16 + split) * 8192;
#pragma unroll
    for (int c = 0; c < 8; ++c) {
        int idx = tid * 4 + c * 1024;
        int row = idx >> 7, col = idx & 127;
        float4 v = *(const float4*)&S[row][col];
        ((float4*)dst)[idx >> 2] = v;
    }
}

// ---------------------------------------------------------------------------
// stage2b: per (b,h): sum partials, +alpha*I, Gauss-Jordan solve on [kk|ktv],
// column softmax, M = Wo_h @ attn^T (MFMA). grid = 64, 256 threads.
// ---------------------------------------------------------------------------
__global__ __launch_bounds__(256) void stage2b_kernel(
    const float* __restrict__ Part,
    const u16* __restrict__ wb,    // [4096][1024] bf16, Wo rows at 3072
    const float* __restrict__ alpha,
    const float* __restrict__ temp,
    u16* __restrict__ Mout)        // [4][1024][1024] bf16
{
    __shared__ float S[64][132];
    __shared__ alignas(16) u16 sAttn[64][72];

    const int tid = threadIdx.x;
    const int wv = tid >> 6, lane = tid & 63;
    const int quad = lane >> 4, lrow = lane & 15;
    const int b = blockIdx.x >> 4, h = blockIdx.x & 15;

    // ---- reduce 16 partials into S ----
    const float* Pb = Part + (size_t)blockIdx.x * 16 * 8192;
#pragma unroll
    for (int c = 0; c < 8; ++c) {
        int idx = tid * 4 + c * 1024;
        float4 a = ((const float4*)Pb)[idx >> 2];
        for (int s = 1; s < 16; ++s) {
            float4 t4 = ((const float4*)(Pb + (size_t)s * 8192))[idx >> 2];
            a.x += t4.x; a.y += t4.y; a.z += t4.z; a.w += t4.w;
        }
        int row = idx >> 7, col = idx & 127;
        *(float4*)&S[row][col] = a;
    }
    __syncthreads();
    if (tid < 64) S[tid][tid] += alpha[0];
    __syncthreads();

    // ---- Gauss-Jordan (no pivoting; kk is SPD diag-dominant) ----
    {
        const int r = tid & 63, cg = tid >> 6;
        for (int p = 0; p < 64; ++p) {
            float pv = S[p][p];
            float f = S[r][p];
            __syncthreads();
            if (r != p) {
                float fp = f / pv;
                int cbase = cg * 32;
#pragma unroll
                for (int cc = 0; cc < 32; ++cc) {
                    int c = cbase + cc;
                    if (c > p) S[r][c] -= fp * S[p][c];
                }
            }
            __syncthreads();
        }
    }

    // ---- X = S[:,64:]/diag; column softmax over rows; bf16 attn ----
    if (tid < 64) {
        const int e = tid;
        const float invT = 1.0f / temp[0];
        float mx = -1e30f;
        for (int d = 0; d < 64; ++d) {
            float xv = (S[d][64 + e] / S[d][d]) * invT;
            S[d][64 + e] = xv;
            mx = fmaxf(mx, xv);
        }
        float sum = 0.f;
        for (int d = 0; d < 64; ++d) {
            float ev = __expf(S[d][64 + e] - mx);
            S[d][64 + e] = ev;
            sum += ev;
        }
        float rs = 1.0f / sum;
        for (int d = 0; d < 64; ++d) sAttn[d][e] = f2bf(S[d][64 + e] * rs);
    }
    __syncthreads();

    // ---- M_b[o][h*64+d] = sum_e Wo[o][h*64+e]*attn[d][e] via MFMA ----
    {
        bf16x8 fB[4][2];
#pragma unroll
        for (int nt = 0; nt < 4; ++nt)
#pragma unroll
            for (int ks = 0; ks < 2; ++ks)
                fB[nt][ks] = *(const bf16x8*)&sAttn[nt * 16 + lrow][ks * 32 + quad * 8];

        const u16* wo = wb + (size_t)3072 * ND + h * 64;
        u16* Mb = Mout + (size_t)b * ND * ND + h * 64;
        for (int i = 0; i < 16; ++i) {
            int mt = wv * 16 + i;
            int oA = mt * 16 + lrow;
            bf16x8 fA[2];
#pragma unroll
            for (int ks = 0; ks < 2; ++ks)
                fA[ks] = *(const bf16x8*)(wo + (size_t)oA * ND + ks * 32 + quad * 8);
#pragma unroll
            for (int nt = 0; nt < 4; ++nt) {
                f32x4 acc = {};
                acc = __builtin_amdgcn_mfma_f32_16x16x32_bf16(fA[0], fB[nt][0], acc, 0, 0, 0);
                acc = __builtin_amdgcn_mfma_f32_16x16x32_bf16(fA[1], fB[nt][1], acc, 0, 0, 0);
#pragma unroll
                for (int r = 0; r < 4; ++r) {
                    int o = mt * 16 + quad * 4 + r;
                    Mb[(size_t)o * ND + nt * 16 + lrow] = f2bf(acc[r]);
                }
            }
        }
    }
}

// ---------------------------------------------------------------------------
// layernorm: one block per row of 1024
// ---------------------------------------------------------------------------
__global__ __launch_bounds__(256) void ln_kernel(
    const float* __restrict__ y, const float* __restrict__ gamma,
    const float* __restrict__ beta, float* __restrict__ out)
{
    const int row = blockIdx.x, tid = threadIdx.x;
    const float4 v = ((const float4*)(y + (size_t)row * ND))[tid];
    float s = v.x + v.y + v.z + v.w;
    float q = v.x * v.x + v.y * v.y + v.z * v.z + v.w * v.w;
#pragma unroll
    for (int off = 32; off > 0; off >>= 1) {
        s += __shfl_xor(s, off, 64);
        q += __shfl_xor(q, off, 64);
    }
    __shared__ float ss[4], sq[4];
    const int wv = tid >> 6;
    if ((tid & 63) == 0) { ss[wv] = s; sq[wv] = q; }
    __syncthreads();
    s = ss[0] + ss[1] + ss[2] + ss[3];
    q = sq[0] + sq[1] + sq[2] + sq[3];
    const float mu = s * (1.0f / ND);
    const float var = q * (1.0f / ND) - mu * mu;
    const float rs = rsqrtf(var + 1e-5f);
    const float4 g = ((const float4*)gamma)[tid];
    const float4 bt = ((const float4*)beta)[tid];
    float4 o;
    o.x = (v.x - mu) * rs * g.x + bt.x;
    o.y = (v.y - mu) * rs * g.y + bt.y;
    o.z = (v.z - mu) * rs * g.z + bt.z;
    o.w = (v.w - mu) * rs * g.w + bt.w;
    ((float4*)(out + (size_t)row * ND))[tid] = o;
}

// ---------------------------------------------------------------------------
extern "C" void kernel_launch(void* const* d_in, const int* in_sizes, int n_in,
                              void* d_out, int out_size, void* d_ws, size_t ws_size,
                              hipStream_t stream)
{
    const float* x     = (const float*)d_in[0];
    const float* Wq    = (const float*)d_in[1];
    const float* Wk    = (const float*)d_in[2];
    const float* Wv    = (const float*)d_in[3];
    const float* Wo    = (const float*)d_in[4];
    const float* bo    = (const float*)d_in[5];
    const float* alpha = (const float*)d_in[6];
    const float* temp  = (const float*)d_in[7];
    const float* gamma = (const float*)d_in[8];
    const float* beta  = (const float*)d_in[9];

    char* ws = (char*)d_ws;
    u16* xb   = (u16*)(ws);                         // 33,554,432 B
    float* Part = (float*)(ws);                     // aliases xb (dead after gemm1)
    u16* wb   = (u16*)(ws + 33554432);              //  8,388,608 B
    u16* qkv  = (u16*)(ws + 41943040);              // 100,663,296 B
    u16* Mb   = (u16*)(ws + 142606336);             //  8,388,608 B
    float* y  = (float*)(ws + 150994944);           // 67,108,864 B  (total 208 MB)
    float* out = (float*)d_out;

    prep_cast<<<dim3(4096), dim3(256), 0, stream>>>(x, Wq, Wk, Wv, Wo, xb, wb);

    // QKV: [16384 x 3072] = x_bf16 @ [Wq;Wk;Wv]^T
    gemm_bt<0><<<dim3(24, 128), dim3(256), 0, stream>>>(
        xb, 1024, wb, 1024, (void*)qkv, 3072, 1024,
        nullptr, nullptr, 1 << 30, (size_t)0);

    // stage2 split: partials across 1024 blocks, then solve on 64 blocks
    stage2a_kernel<<<dim3(64, 16), dim3(256), 0, stream>>>(qkv, Part);
    stage2b_kernel<<<dim3(64), dim3(256), 0, stream>>>(Part, wb, alpha, temp, Mb);

    // y = q @ M_b^T + bo + x   (per-batch weights)
    gemm_bt<1><<<dim3(8, 128), dim3(256), 0, stream>>>(
        qkv, 3072, Mb, 1024, (void*)y, 1024, 1024,
        bo, x, 4096, (size_t)(1024 * 1024));

    ln_kernel<<<dim3(16384), dim3(256), 0, stream>>>(y, gamma, beta, out);
}

// Round 3
// 440.988 us; speedup vs baseline: 1.2777x; 1.2092x over previous
//
#include <hip/hip_runtime.h>
#include <cstdint>
#include <cstddef>

typedef unsigned short u16;
typedef __bf16 bf16x8 __attribute__((ext_vector_type(8)));
typedef float f32x4 __attribute__((ext_vector_type(4)));
typedef u16 u16x8 __attribute__((ext_vector_type(8)));
typedef u16 u16x4 __attribute__((ext_vector_type(4)));

#define NB 4
#define NN 4096
#define ND 1024
#define NH 16
#define NTOK (NB * NN)   // 16384

__device__ __forceinline__ u16 f2bf(float f) {
    unsigned u = __float_as_uint(f);
    u += 0x7fffu + ((u >> 16) & 1u);
    return (u16)(u >> 16);
}

__device__ __forceinline__ void gload_lds16(const void* g, void* l) {
    __builtin_amdgcn_global_load_lds(
        (const __attribute__((address_space(1))) void*)g,
        (__attribute__((address_space(3))) void*)l, 16, 0, 0);
}

// ---------------------------------------------------------------------------
// prep: cast x (fp32->bf16) and Wq|Wk|Wv|Wo into one bf16 weight block
// ---------------------------------------------------------------------------
__global__ __launch_bounds__(256) void prep_cast(
    const float* __restrict__ x,
    const float* __restrict__ wq, const float* __restrict__ wk,
    const float* __restrict__ wv, const float* __restrict__ wo,
    u16* __restrict__ xb, u16* __restrict__ wb)
{
    const int n_x4 = (NTOK * ND) / 4;       // 4194304
    const int n_w4 = (ND * ND) / 4;         // 262144 per weight
    const int total = n_x4 + 4 * n_w4;      // 5242880
    for (int i = blockIdx.x * blockDim.x + threadIdx.x; i < total;
         i += gridDim.x * blockDim.x) {
        float4 v;
        u16* dst;
        if (i < n_x4) {
            v = ((const float4*)x)[i];
            dst = xb + (size_t)i * 4;
        } else {
            int j = i - n_x4;
            int w = j / n_w4;
            int off = j - w * n_w4;
            const float* src = (w == 0) ? wq : (w == 1) ? wk : (w == 2) ? wv : wo;
            v = ((const float4*)src)[off];
            dst = wb + (size_t)j * 4;
        }
        u16x4 o;
        o[0] = f2bf(v.x); o[1] = f2bf(v.y); o[2] = f2bf(v.z); o[3] = f2bf(v.w);
        *(u16x4*)dst = o;
    }
}

// ---------------------------------------------------------------------------
// gemm_bt: C[m][n] = sum_k A[m][k]*B[n][k]  (both row-major along k), bf16 MFMA
// 128x128 tile, BK=32, 256 threads = 4 waves (2x2 of 64x64)
// OUT_MODE 0: bf16 store; OUT_MODE 1: f32 store + bias[col] + resid[m][col]
// ---------------------------------------------------------------------------
template <int OUT_MODE>
__global__ __launch_bounds__(256, 2) void gemm_bt(
    const u16* __restrict__ A, int lda,
    const u16* __restrict__ Bw, int ldb,
    void* __restrict__ Cout, int ldc, int K,
    const float* __restrict__ bias, const float* __restrict__ resid,
    int rows_per_batch, size_t b_stride)
{
    __shared__ alignas(16) u16 lA[128 * 32];
    __shared__ alignas(16) u16 lB[128 * 32];

    const int tid = threadIdx.x;
    const int wv = tid >> 6, lane = tid & 63;
    const int quad = lane >> 4, lrow = lane & 15;
    const int row0 = blockIdx.y * 128, col0 = blockIdx.x * 128;
    const int wm = (wv >> 1) * 64, wn = (wv & 1) * 64;

    const u16* Bp = Bw + (b_stride ? (size_t)(row0 / rows_per_batch) * b_stride : 0);

    f32x4 acc[4][4] = {};

    const int srow = lane >> 2;          // 0..15 within chunk
    const int scolh = (lane & 3) * 8;    // halfword col in k

    for (int k0 = 0; k0 < K; k0 += 32) {
        __syncthreads();
        const int c0 = wv * 2;
#pragma unroll
        for (int c = c0; c < c0 + 2; ++c) {
            int row = c * 16 + srow;
            gload_lds16(A + (size_t)(row0 + row) * lda + k0 + scolh, &lA[c * 512]);
            gload_lds16(Bp + (size_t)(col0 + row) * ldb + k0 + scolh, &lB[c * 512]);
        }
        __syncthreads();

        bf16x8 af[4], bfv[4];
#pragma unroll
        for (int t = 0; t < 4; ++t)
            af[t] = *(const bf16x8*)&lA[(wm + t * 16 + lrow) * 32 + quad * 8];
#pragma unroll
        for (int t = 0; t < 4; ++t)
            bfv[t] = *(const bf16x8*)&lB[(wn + t * 16 + lrow) * 32 + quad * 8];

#pragma unroll
        for (int mt = 0; mt < 4; ++mt)
#pragma unroll
            for (int nt = 0; nt < 4; ++nt)
                acc[mt][nt] = __builtin_amdgcn_mfma_f32_16x16x32_bf16(
                    af[mt], bfv[nt], acc[mt][nt], 0, 0, 0);
    }

    // epilogue; C/D layout: col = lane&15, row = quad*4 + reg
#pragma unroll
    for (int mt = 0; mt < 4; ++mt)
#pragma unroll
        for (int nt = 0; nt < 4; ++nt)
#pragma unroll
            for (int r = 0; r < 4; ++r) {
                int grow = row0 + wm + mt * 16 + quad * 4 + r;
                int gcol = col0 + wn + nt * 16 + lrow;
                if (OUT_MODE == 0) {
                    ((u16*)Cout)[(size_t)grow * ldc + gcol] = f2bf(acc[mt][nt][r]);
                } else {
                    float vv = acc[mt][nt][r] + bias[gcol] +
                               resid[(size_t)grow * ldc + gcol];
                    ((float*)Cout)[(size_t)grow * ldc + gcol] = vv;
                }
            }
}

// ---------------------------------------------------------------------------
// stage2a: partial kk/ktv per (b,h,split). grid = (64, 16), 256 threads.
// Each block covers 256 tokens; each wave 64 tokens (2 iters of 32).
// Writes fp32 partial tile [64][128] (kk | ktv) to Part[bh*16+split].
// ---------------------------------------------------------------------------
__global__ __launch_bounds__(256) void stage2a_kernel(
    const u16* __restrict__ qkv,   // [16384][3072] bf16 (q|k|v)
    float* __restrict__ Part)      // [64*16][64*128] fp32
{
    __shared__ alignas(16) u16 sKt[4][64][40];   // per-wave K^T tile (pad 40)
    __shared__ alignas(16) u16 sVt[4][64][40];
    __shared__ float S[64][132];

    const int tid = threadIdx.x;
    const int wv = tid >> 6, lane = tid & 63;
    const int quad = lane >> 4, lrow = lane & 15;
    const int bh = blockIdx.x, split = blockIdx.y;
    const int b = bh >> 4, h = bh & 15;

    f32x4 akk[4][4] = {};
    f32x4 aktv[4][4] = {};
    const u16* kbase = qkv + ND + h * 64;
    const u16* vbase = qkv + 2 * ND + h * 64;
    const size_t tok0 = (size_t)b * NN;

    for (int it = 0; it < 2; ++it) {
        const int n0 = split * 256 + wv * 64 + it * 32;
#pragma unroll
        for (int pass = 0; pass < 4; ++pass) {
            int nl = pass * 8 + (lane >> 3);
            int d0 = (lane & 7) * 8;
            size_t roff = (tok0 + n0 + nl) * 3072 + d0;
            u16x8 kvv = *(const u16x8*)(kbase + roff);
            u16x8 vvv = *(const u16x8*)(vbase + roff);
#pragma unroll
            for (int j = 0; j < 8; ++j) {
                sKt[wv][d0 + j][nl] = kvv[j];
                sVt[wv][d0 + j][nl] = vvv[j];
            }
        }
        bf16x8 fK[4], fV[4];
#pragma unroll
        for (int t = 0; t < 4; ++t) {
            fK[t] = *(const bf16x8*)&sKt[wv][t * 16 + lrow][quad * 8];
            fV[t] = *(const bf16x8*)&sVt[wv][t * 16 + lrow][quad * 8];
        }
#pragma unroll
        for (int mt = 0; mt < 4; ++mt)
#pragma unroll
            for (int et = 0; et < 4; ++et) {
                akk[mt][et] = __builtin_amdgcn_mfma_f32_16x16x32_bf16(
                    fK[mt], fK[et], akk[mt][et], 0, 0, 0);
                aktv[mt][et] = __builtin_amdgcn_mfma_f32_16x16x32_bf16(
                    fK[mt], fV[et], aktv[mt][et], 0, 0, 0);
            }
    }

    // cross-wave reduce into S
    for (int w = 0; w < 4; ++w) {
        if (wv == w) {
#pragma unroll
            for (int mt = 0; mt < 4; ++mt)
#pragma unroll
                for (int et = 0; et < 4; ++et)
#pragma unroll
                    for (int r = 0; r < 4; ++r) {
                        int row = mt * 16 + quad * 4 + r;
                        int col = et * 16 + lrow;
                        if (w == 0) {
                            S[row][col] = akk[mt][et][r];
                            S[row][64 + col] = aktv[mt][et][r];
                        } else {
                            S[row][col] += akk[mt][et][r];
                            S[row][64 + col] += aktv[mt][et][r];
                        }
                    }
        }
        __syncthreads();
    }

    // coalesced fp32 write-out
    float* dst = Part + (size_t)(bh * 16 + split) * 8192;
#pragma unroll
    for (int c = 0; c < 8; ++c) {
        int idx = tid * 4 + c * 1024;
        int row = idx >> 7, col = idx & 127;
        float4 v = *(const float4*)&S[row][col];
        ((float4*)dst)[idx >> 2] = v;
    }
}

// ---------------------------------------------------------------------------
// stage2b: per (b,h): sum partials, +alpha*I, REGISTER-RESIDENT Gauss-Jordan
// (thread (r=lane, colgroup=wave) owns 32 floats; pivot row broadcast via
// v_readlane within each wave, pivot column via one conflict-free LDS write;
// 1 barrier/pivot), wave-shuffle column softmax, M = Wo_h @ attn^T (MFMA).
// grid = 64, 256 threads.
// ---------------------------------------------------------------------------
__global__ __launch_bounds__(256) void stage2b_kernel(
    const float* __restrict__ Part,
    const u16* __restrict__ wb,    // [4096][1024] bf16, Wo rows at 3072
    const float* __restrict__ alpha,
    const float* __restrict__ temp,
    u16* __restrict__ Mout)        // [4][1024][1024] bf16
{
    __shared__ float S[64][132];
    __shared__ float colbuf[2][64];
    __shared__ alignas(16) u16 sAttn[64][72];

    const int tid = threadIdx.x;
    const int wv = tid >> 6, lane = tid & 63;   // row r = lane, colgroup = wv
    const int quad = lane >> 4, lrow = lane & 15;
    const int b = blockIdx.x >> 4, h = blockIdx.x & 15;

    // ---- reduce 16 partials into S (coalesced float4 reads) ----
    const float* Pb = Part + (size_t)blockIdx.x * 16 * 8192;
#pragma unroll
    for (int c = 0; c < 8; ++c) {
        int idx = tid * 4 + c * 1024;
        float4 a = ((const float4*)Pb)[idx >> 2];
#pragma unroll
        for (int s = 1; s < 16; ++s) {
            float4 t4 = ((const float4*)(Pb + (size_t)s * 8192))[idx >> 2];
            a.x += t4.x; a.y += t4.y; a.z += t4.z; a.w += t4.w;
        }
        int row = idx >> 7, col = idx & 127;
        *(float4*)&S[row][col] = a;
    }
    __syncthreads();

    // ---- load my 32 columns into registers; + alpha on diagonal ----
    const float aval = alpha[0];
    const int c0 = wv * 32;
    float R[32];
#pragma unroll
    for (int j = 0; j < 32; ++j) {
        R[j] = S[lane][c0 + j];
        if (c0 + j == lane) R[j] += aval;
    }
    // colbuf for pivot 0: wave 0 holds column 0 in R[0]
    if (wv == 0) colbuf[0][lane] = R[0];
    __syncthreads();

    // ---- Gauss-Jordan, registers + readlane (no pivoting: SPD dominant) ----
    float mydiag = 1.0f;
    for (int p = 0; p < 64; ++p) {
        const int cur = p & 1;
        float cv = colbuf[cur][lane];     // S[r][p], conflict-free stride-1
        float pv = colbuf[cur][p];        // S[p][p], broadcast
        if (p == lane) mydiag = pv;       // diag never changes after pivot p
        float m = (lane == p) ? 0.0f : cv * __builtin_amdgcn_rcpf(pv);
#pragma unroll
        for (int j = 0; j < 32; ++j) {
            float rowv = __uint_as_float(
                __builtin_amdgcn_readlane(__float_as_uint(R[j]), p));
            R[j] -= m * rowv;             // lane p: m=0 -> row p preserved
        }
        if (p < 63) {
            int pn = p + 1;
            if (wv == (pn >> 5)) colbuf[cur ^ 1][lane] = R[pn & 31];
        }
        __syncthreads();
    }

    // ---- right half: X = R/diag; column softmax over rows via shuffles ----
    if (wv >= 2) {
        const float idg = __builtin_amdgcn_rcpf(mydiag) * (1.0f / temp[0]);
#pragma unroll
        for (int j = 0; j < 32; ++j) {
            float xv = R[j] * idg;
            float mx = xv;
#pragma unroll
            for (int off = 32; off > 0; off >>= 1)
                mx = fmaxf(mx, __shfl_xor(mx, off, 64));
            float ev = __expf(xv - mx);
            float sum = ev;
#pragma unroll
            for (int off = 32; off > 0; off >>= 1)
                sum += __shfl_xor(sum, off, 64);
            sAttn[lane][(wv - 2) * 32 + j] = f2bf(ev * __builtin_amdgcn_rcpf(sum));
        }
    }
    __syncthreads();

    // ---- M_b[o][h*64+d] = sum_e Wo[o][h*64+e]*attn[d][e] via MFMA ----
    {
        bf16x8 fB[4][2];
#pragma unroll
        for (int nt = 0; nt < 4; ++nt)
#pragma unroll
            for (int ks = 0; ks < 2; ++ks)
                fB[nt][ks] = *(const bf16x8*)&sAttn[nt * 16 + lrow][ks * 32 + quad * 8];

        const u16* wo = wb + (size_t)3072 * ND + h * 64;
        u16* Mb = Mout + (size_t)b * ND * ND + h * 64;
        for (int i = 0; i < 16; ++i) {
            int mt = wv * 16 + i;
            int oA = mt * 16 + lrow;
            bf16x8 fA[2];
#pragma unroll
            for (int ks = 0; ks < 2; ++ks)
                fA[ks] = *(const bf16x8*)(wo + (size_t)oA * ND + ks * 32 + quad * 8);
#pragma unroll
            for (int nt = 0; nt < 4; ++nt) {
                f32x4 acc = {};
                acc = __builtin_amdgcn_mfma_f32_16x16x32_bf16(fA[0], fB[nt][0], acc, 0, 0, 0);
                acc = __builtin_amdgcn_mfma_f32_16x16x32_bf16(fA[1], fB[nt][1], acc, 0, 0, 0);
#pragma unroll
                for (int r = 0; r < 4; ++r) {
                    int o = mt * 16 + quad * 4 + r;
                    Mb[(size_t)o * ND + nt * 16 + lrow] = f2bf(acc[r]);
                }
            }
        }
    }
}

// ---------------------------------------------------------------------------
// layernorm: one block per row of 1024
// ---------------------------------------------------------------------------
__global__ __launch_bounds__(256) void ln_kernel(
    const float* __restrict__ y, const float* __restrict__ gamma,
    const float* __restrict__ beta, float* __restrict__ out)
{
    const int row = blockIdx.x, tid = threadIdx.x;
    const float4 v = ((const float4*)(y + (size_t)row * ND))[tid];
    float s = v.x + v.y + v.z + v.w;
    float q = v.x * v.x + v.y * v.y + v.z * v.z + v.w * v.w;
#pragma unroll
    for (int off = 32; off > 0; off >>= 1) {
        s += __shfl_xor(s, off, 64);
        q += __shfl_xor(q, off, 64);
    }
    __shared__ float ss[4], sq[4];
    const int wv = tid >> 6;
    if ((tid & 63) == 0) { ss[wv] = s; sq[wv] = q; }
    __syncthreads();
    s = ss[0] + ss[1] + ss[2] + ss[3];
    q = sq[0] + sq[1] + sq[2] + sq[3];
    const float mu = s * (1.0f / ND);
    const float var = q * (1.0f / ND) - mu * mu;
    const float rs = rsqrtf(var + 1e-5f);
    const float4 g = ((const float4*)gamma)[tid];
    const float4 bt = ((const float4*)beta)[tid];
    float4 o;
    o.x = (v.x - mu) * rs * g.x + bt.x;
    o.y = (v.y - mu) * rs * g.y + bt.y;
    o.z = (v.z - mu) * rs * g.z + bt.z;
    o.w = (v.w - mu) * rs * g.w + bt.w;
    ((float4*)(out + (size_t)row * ND))[tid] = o;
}

// ---------------------------------------------------------------------------
extern "C" void kernel_launch(void* const* d_in, const int* in_sizes, int n_in,
                              void* d_out, int out_size, void* d_ws, size_t ws_size,
                              hipStream_t stream)
{
    const float* x     = (const float*)d_in[0];
    const float* Wq    = (const float*)d_in[1];
    const float* Wk    = (const float*)d_in[2];
    const float* Wv    = (const float*)d_in[3];
    const float* Wo    = (const float*)d_in[4];
    const float* bo    = (const float*)d_in[5];
    const float* alpha = (const float*)d_in[6];
    const float* temp  = (const float*)d_in[7];
    const float* gamma = (const float*)d_in[8];
    const float* beta  = (const float*)d_in[9];

    char* ws = (char*)d_ws;
    u16* xb   = (u16*)(ws);                         // 33,554,432 B
    float* Part = (float*)(ws);                     // aliases xb (dead after gemm1)
    u16* wb   = (u16*)(ws + 33554432);              //  8,388,608 B
    u16* qkv  = (u16*)(ws + 41943040);              // 100,663,296 B
    u16* Mb   = (u16*)(ws + 142606336);             //  8,388,608 B
    float* y  = (float*)(ws + 150994944);           // 67,108,864 B  (total 208 MB)
    float* out = (float*)d_out;

    prep_cast<<<dim3(4096), dim3(256), 0, stream>>>(x, Wq, Wk, Wv, Wo, xb, wb);

    // QKV: [16384 x 3072] = x_bf16 @ [Wq;Wk;Wv]^T
    gemm_bt<0><<<dim3(24, 128), dim3(256), 0, stream>>>(
        xb, 1024, wb, 1024, (void*)qkv, 3072, 1024,
        nullptr, nullptr, 1 << 30, (size_t)0);

    // stage2 split: partials across 1024 blocks, then solve on 64 blocks
    stage2a_kernel<<<dim3(64, 16), dim3(256), 0, stream>>>(qkv, Part);
    stage2b_kernel<<<dim3(64), dim3(256), 0, stream>>>(Part, wb, alpha, temp, Mb);

    // y = q @ M_b^T + bo + x   (per-batch weights)
    gemm_bt<1><<<dim3(8, 128), dim3(256), 0, stream>>>(
        qkv, 3072, Mb, 1024, (void*)y, 1024, 1024,
        bo, x, 4096, (size_t)(1024 * 1024));

    ln_kernel<<<dim3(16384), dim3(256), 0, stream>>>(y, gamma, beta, out);
}

// Round 4
// 424.013 us; speedup vs baseline: 1.3289x; 1.0400x over previous
//
#include <hip/hip_runtime.h>
#include <cstdint>
#include <cstddef>

typedef unsigned short u16;
typedef __bf16 bf16x8 __attribute__((ext_vector_type(8)));
typedef float f32x4 __attribute__((ext_vector_type(4)));
typedef u16 u16x8 __attribute__((ext_vector_type(8)));
typedef u16 u16x4 __attribute__((ext_vector_type(4)));

#define NB 4
#define NN 4096
#define ND 1024
#define NH 16
#define NTOK (NB * NN)   // 16384

__device__ __forceinline__ u16 f2bf(float f) {
    unsigned u = __float_as_uint(f);
    u += 0x7fffu + ((u >> 16) & 1u);
    return (u16)(u >> 16);
}

__device__ __forceinline__ void gload_lds16(const void* g, void* l) {
    __builtin_amdgcn_global_load_lds(
        (const __attribute__((address_space(1))) void*)g,
        (__attribute__((address_space(3))) void*)l, 16, 0, 0);
}

// ---------------------------------------------------------------------------
// prep: cast x (fp32->bf16) and Wq|Wk|Wv|Wo into one bf16 weight block
// ---------------------------------------------------------------------------
__global__ __launch_bounds__(256) void prep_cast(
    const float* __restrict__ x,
    const float* __restrict__ wq, const float* __restrict__ wk,
    const float* __restrict__ wv, const float* __restrict__ wo,
    u16* __restrict__ xb, u16* __restrict__ wb)
{
    const int n_x4 = (NTOK * ND) / 4;       // 4194304
    const int n_w4 = (ND * ND) / 4;         // 262144 per weight (pow2 -> shifts)
    const int total = n_x4 + 4 * n_w4;      // 5242880
    for (int i = blockIdx.x * blockDim.x + threadIdx.x; i < total;
         i += gridDim.x * blockDim.x) {
        float4 v;
        u16* dst;
        if (i < n_x4) {
            v = ((const float4*)x)[i];
            dst = xb + (size_t)i * 4;
        } else {
            int j = i - n_x4;
            int w = j / n_w4;
            int off = j - w * n_w4;
            const float* src = (w == 0) ? wq : (w == 1) ? wk : (w == 2) ? wv : wo;
            v = ((const float4*)src)[off];
            dst = wb + (size_t)j * 4;
        }
        u16x4 o;
        o[0] = f2bf(v.x); o[1] = f2bf(v.y); o[2] = f2bf(v.z); o[3] = f2bf(v.w);
        *(u16x4*)dst = o;
    }
}

// ---------------------------------------------------------------------------
// gemm_bt: C[m][n] = sum_k A[m][k]*B[n][k], bf16 MFMA.
// Block 256x128, BK=64, 4 waves, wave tile 128x64 (acc 128 VGPR).
// LDS rows are 8 chunks of 16B; chunk c of row r stored at c^(r&7) (bank
// swizzle). gload source lane-map permuted to match (legal: wave-uniform
// base + lane*16 dest preserved; source stays within one 128B row run).
// OUT_MODE 0: bf16 store; OUT_MODE 1: f32 store + bias[col] + resid[m][col]
// ---------------------------------------------------------------------------
template <int OUT_MODE>
__global__ __launch_bounds__(256, 2) void gemm_bt(
    const u16* __restrict__ A, int lda,
    const u16* __restrict__ Bw, int ldb,
    void* __restrict__ Cout, int ldc, int K,
    const float* __restrict__ bias, const float* __restrict__ resid,
    int rows_per_batch, size_t b_stride)
{
    __shared__ alignas(16) u16 lA[256 * 64];   // 32 KB
    __shared__ alignas(16) u16 lB[128 * 64];   // 16 KB

    const int tid = threadIdx.x;
    const int wv = tid >> 6, lane = tid & 63;
    const int quad = lane >> 4, lrow = lane & 15;
    const int row0 = blockIdx.y * 256, col0 = blockIdx.x * 128;
    const int wm = (wv >> 1) * 128, wn = (wv & 1) * 64;

    const u16* Bp = Bw + (b_stride ? (size_t)(row0 / rows_per_batch) * b_stride : 0);

    f32x4 acc[8][4] = {};

    const int srow = lane >> 3;                    // 0..7 (local row in 8-row seg)
    const int cswE = ((lane & 7) ^ srow) * 8;      // swizzled src col, elements

    for (int k0 = 0; k0 < K; k0 += 64) {
        __syncthreads();
        // A: 8 insts/wave, each stages 8 rows x 128B; B: 4 insts/wave
#pragma unroll
        for (int i = 0; i < 8; ++i) {
            int rb = wv * 64 + i * 8;
            gload_lds16(A + (size_t)(row0 + rb + srow) * lda + k0 + cswE,
                        &lA[rb * 64]);
        }
#pragma unroll
        for (int i = 0; i < 4; ++i) {
            int rb = wv * 32 + i * 8;
            gload_lds16(Bp + (size_t)(col0 + rb + srow) * ldb + k0 + cswE,
                        &lB[rb * 64]);
        }
        __syncthreads();

#pragma unroll
        for (int kc = 0; kc < 2; ++kc) {
            const int ch = ((kc * 4 + quad) ^ (lrow & 7)) * 8;
            bf16x8 bfv[4];
#pragma unroll
            for (int t = 0; t < 4; ++t)
                bfv[t] = *(const bf16x8*)&lB[(wn + t * 16 + lrow) * 64 + ch];
#pragma unroll
            for (int mt = 0; mt < 8; ++mt) {
                bf16x8 af = *(const bf16x8*)&lA[(wm + mt * 16 + lrow) * 64 + ch];
#pragma unroll
                for (int nt = 0; nt < 4; ++nt)
                    acc[mt][nt] = __builtin_amdgcn_mfma_f32_16x16x32_bf16(
                        af, bfv[nt], acc[mt][nt], 0, 0, 0);
            }
        }
    }

    // epilogue; C/D layout: col = lane&15, row = quad*4 + reg
    float bvals[4];
    if (OUT_MODE == 1) {
#pragma unroll
        for (int nt = 0; nt < 4; ++nt)
            bvals[nt] = bias[col0 + wn + nt * 16 + lrow];
    }
#pragma unroll
    for (int mt = 0; mt < 8; ++mt)
#pragma unroll
        for (int nt = 0; nt < 4; ++nt)
#pragma unroll
            for (int r = 0; r < 4; ++r) {
                int grow = row0 + wm + mt * 16 + quad * 4 + r;
                int gcol = col0 + wn + nt * 16 + lrow;
                if (OUT_MODE == 0) {
                    ((u16*)Cout)[(size_t)grow * ldc + gcol] = f2bf(acc[mt][nt][r]);
                } else {
                    float vv = acc[mt][nt][r] + bvals[nt] +
                               resid[(size_t)grow * ldc + gcol];
                    ((float*)Cout)[(size_t)grow * ldc + gcol] = vv;
                }
            }
}

// ---------------------------------------------------------------------------
// stage2a: partial kk/ktv per (b,h,split). grid = (64, 16), 256 threads.
// Each block covers 256 tokens; each wave 64 tokens (2 iters of 32).
// Writes fp32 partial tile [64][128] (kk | ktv) to Part[bh*16+split].
// ---------------------------------------------------------------------------
__global__ __launch_bounds__(256) void stage2a_kernel(
    const u16* __restrict__ qkv,   // [16384][3072] bf16 (q|k|v)
    float* __restrict__ Part)      // [64*16][64*128] fp32
{
    __shared__ alignas(16) u16 sKt[4][64][40];   // per-wave K^T tile (pad 40)
    __shared__ alignas(16) u16 sVt[4][64][40];
    __shared__ float S[64][132];

    const int tid = threadIdx.x;
    const int wv = tid >> 6, lane = tid & 63;
    const int quad = lane >> 4, lrow = lane & 15;
    const int bh = blockIdx.x, split = blockIdx.y;
    const int b = bh >> 4, h = bh & 15;

    f32x4 akk[4][4] = {};
    f32x4 aktv[4][4] = {};
    const u16* kbase = qkv + ND + h * 64;
    const u16* vbase = qkv + 2 * ND + h * 64;
    const size_t tok0 = (size_t)b * NN;

    for (int it = 0; it < 2; ++it) {
        const int n0 = split * 256 + wv * 64 + it * 32;
#pragma unroll
        for (int pass = 0; pass < 4; ++pass) {
            int nl = pass * 8 + (lane >> 3);
            int d0 = (lane & 7) * 8;
            size_t roff = (tok0 + n0 + nl) * 3072 + d0;
            u16x8 kvv = *(const u16x8*)(kbase + roff);
            u16x8 vvv = *(const u16x8*)(vbase + roff);
#pragma unroll
            for (int j = 0; j < 8; ++j) {
                sKt[wv][d0 + j][nl] = kvv[j];
                sVt[wv][d0 + j][nl] = vvv[j];
            }
        }
        bf16x8 fK[4], fV[4];
#pragma unroll
        for (int t = 0; t < 4; ++t) {
            fK[t] = *(const bf16x8*)&sKt[wv][t * 16 + lrow][quad * 8];
            fV[t] = *(const bf16x8*)&sVt[wv][t * 16 + lrow][quad * 8];
        }
#pragma unroll
        for (int mt = 0; mt < 4; ++mt)
#pragma unroll
            for (int et = 0; et < 4; ++et) {
                akk[mt][et] = __builtin_amdgcn_mfma_f32_16x16x32_bf16(
                    fK[mt], fK[et], akk[mt][et], 0, 0, 0);
                aktv[mt][et] = __builtin_amdgcn_mfma_f32_16x16x32_bf16(
                    fK[mt], fV[et], aktv[mt][et], 0, 0, 0);
            }
    }

    // cross-wave reduce into S
    for (int w = 0; w < 4; ++w) {
        if (wv == w) {
#pragma unroll
            for (int mt = 0; mt < 4; ++mt)
#pragma unroll
                for (int et = 0; et < 4; ++et)
#pragma unroll
                    for (int r = 0; r < 4; ++r) {
                        int row = mt * 16 + quad * 4 + r;
                        int col = et * 16 + lrow;
                        if (w == 0) {
                            S[row][col] = akk[mt][et][r];
                            S[row][64 + col] = aktv[mt][et][r];
                        } else {
                            S[row][col] += akk[mt][et][r];
                            S[row][64 + col] += aktv[mt][et][r];
                        }
                    }
        }
        __syncthreads();
    }

    // coalesced fp32 write-out
    float* dst = Part + (size_t)(bh * 16 + split) * 8192;
#pragma unroll
    for (int c = 0; c < 8; ++c) {
        int idx = tid * 4 + c * 1024;
        int row = idx >> 7, col = idx & 127;
        float4 v = *(const float4*)&S[row][col];
        ((float4*)dst)[idx >> 2] = v;
    }
}

// ---------------------------------------------------------------------------
// stage2b: per (b,h): sum partials, +alpha*I, REGISTER-RESIDENT Gauss-Jordan
// (thread (r=lane, colgroup=wave) owns 32 floats; pivot row broadcast via
// v_readlane within each wave, pivot column via one conflict-free LDS write;
// 1 barrier/pivot), wave-shuffle column softmax, M = Wo_h @ attn^T (MFMA).
// grid = 64, 256 threads.
// ---------------------------------------------------------------------------
__global__ __launch_bounds__(256) void stage2b_kernel(
    const float* __restrict__ Part,
    const u16* __restrict__ wb,    // [4096][1024] bf16, Wo rows at 3072
    const float* __restrict__ alpha,
    const float* __restrict__ temp,
    u16* __restrict__ Mout)        // [4][1024][1024] bf16
{
    __shared__ float S[64][132];
    __shared__ float colbuf[2][64];
    __shared__ alignas(16) u16 sAttn[64][72];

    const int tid = threadIdx.x;
    const int wv = tid >> 6, lane = tid & 63;   // row r = lane, colgroup = wv
    const int quad = lane >> 4, lrow = lane & 15;
    const int b = blockIdx.x >> 4, h = blockIdx.x & 15;

    // ---- reduce 16 partials into S (coalesced float4 reads) ----
    const float* Pb = Part + (size_t)blockIdx.x * 16 * 8192;
#pragma unroll
    for (int c = 0; c < 8; ++c) {
        int idx = tid * 4 + c * 1024;
        float4 a = ((const float4*)Pb)[idx >> 2];
#pragma unroll
        for (int s = 1; s < 16; ++s) {
            float4 t4 = ((const float4*)(Pb + (size_t)s * 8192))[idx >> 2];
            a.x += t4.x; a.y += t4.y; a.z += t4.z; a.w += t4.w;
        }
        int row = idx >> 7, col = idx & 127;
        *(float4*)&S[row][col] = a;
    }
    __syncthreads();

    // ---- load my 32 columns into registers; + alpha on diagonal ----
    const float aval = alpha[0];
    const int c0 = wv * 32;
    float R[32];
#pragma unroll
    for (int j = 0; j < 32; ++j) {
        R[j] = S[lane][c0 + j];
        if (c0 + j == lane) R[j] += aval;
    }
    // colbuf for pivot 0: wave 0 holds column 0 in R[0]
    if (wv == 0) colbuf[0][lane] = R[0];
    __syncthreads();

    // ---- Gauss-Jordan, registers + readlane (no pivoting: SPD dominant) ----
    float mydiag = 1.0f;
    for (int p = 0; p < 64; ++p) {
        const int cur = p & 1;
        float cv = colbuf[cur][lane];     // S[r][p], conflict-free stride-1
        float pv = colbuf[cur][p];        // S[p][p], broadcast
        if (p == lane) mydiag = pv;       // diag never changes after pivot p
        float m = (lane == p) ? 0.0f : cv * __builtin_amdgcn_rcpf(pv);
#pragma unroll
        for (int j = 0; j < 32; ++j) {
            float rowv = __uint_as_float(
                __builtin_amdgcn_readlane(__float_as_uint(R[j]), p));
            R[j] -= m * rowv;             // lane p: m=0 -> row p preserved
        }
        if (p < 63) {
            int pn = p + 1;
            if (wv == (pn >> 5)) colbuf[cur ^ 1][lane] = R[pn & 31];
        }
        __syncthreads();
    }

    // ---- right half: X = R/diag; column softmax over rows via shuffles ----
    if (wv >= 2) {
        const float idg = __builtin_amdgcn_rcpf(mydiag) * (1.0f / temp[0]);
#pragma unroll
        for (int j = 0; j < 32; ++j) {
            float xv = R[j] * idg;
            float mx = xv;
#pragma unroll
            for (int off = 32; off > 0; off >>= 1)
                mx = fmaxf(mx, __shfl_xor(mx, off, 64));
            float ev = __expf(xv - mx);
            float sum = ev;
#pragma unroll
            for (int off = 32; off > 0; off >>= 1)
                sum += __shfl_xor(sum, off, 64);
            sAttn[lane][(wv - 2) * 32 + j] = f2bf(ev * __builtin_amdgcn_rcpf(sum));
        }
    }
    __syncthreads();

    // ---- M_b[o][h*64+d] = sum_e Wo[o][h*64+e]*attn[d][e] via MFMA ----
    {
        bf16x8 fB[4][2];
#pragma unroll
        for (int nt = 0; nt < 4; ++nt)
#pragma unroll
            for (int ks = 0; ks < 2; ++ks)
                fB[nt][ks] = *(const bf16x8*)&sAttn[nt * 16 + lrow][ks * 32 + quad * 8];

        const u16* wo = wb + (size_t)3072 * ND + h * 64;
        u16* Mb = Mout + (size_t)b * ND * ND + h * 64;
        for (int i = 0; i < 16; ++i) {
            int mt = wv * 16 + i;
            int oA = mt * 16 + lrow;
            bf16x8 fA[2];
#pragma unroll
            for (int ks = 0; ks < 2; ++ks)
                fA[ks] = *(const bf16x8*)(wo + (size_t)oA * ND + ks * 32 + quad * 8);
#pragma unroll
            for (int nt = 0; nt < 4; ++nt) {
                f32x4 acc = {};
                acc = __builtin_amdgcn_mfma_f32_16x16x32_bf16(fA[0], fB[nt][0], acc, 0, 0, 0);
                acc = __builtin_amdgcn_mfma_f32_16x16x32_bf16(fA[1], fB[nt][1], acc, 0, 0, 0);
#pragma unroll
                for (int r = 0; r < 4; ++r) {
                    int o = mt * 16 + quad * 4 + r;
                    Mb[(size_t)o * ND + nt * 16 + lrow] = f2bf(acc[r]);
                }
            }
        }
    }
}

// ---------------------------------------------------------------------------
// layernorm: one block per row of 1024
// ---------------------------------------------------------------------------
__global__ __launch_bounds__(256) void ln_kernel(
    const float* __restrict__ y, const float* __restrict__ gamma,
    const float* __restrict__ beta, float* __restrict__ out)
{
    const int row = blockIdx.x, tid = threadIdx.x;
    const float4 v = ((const float4*)(y + (size_t)row * ND))[tid];
    float s = v.x + v.y + v.z + v.w;
    float q = v.x * v.x + v.y * v.y + v.z * v.z + v.w * v.w;
#pragma unroll
    for (int off = 32; off > 0; off >>= 1) {
        s += __shfl_xor(s, off, 64);
        q += __shfl_xor(q, off, 64);
    }
    __shared__ float ss[4], sq[4];
    const int wv = tid >> 6;
    if ((tid & 63) == 0) { ss[wv] = s; sq[wv] = q; }
    __syncthreads();
    s = ss[0] + ss[1] + ss[2] + ss[3];
    q = sq[0] + sq[1] + sq[2] + sq[3];
    const float mu = s * (1.0f / ND);
    const float var = q * (1.0f / ND) - mu * mu;
    const float rs = rsqrtf(var + 1e-5f);
    const float4 g = ((const float4*)gamma)[tid];
    const float4 bt = ((const float4*)beta)[tid];
    float4 o;
    o.x = (v.x - mu) * rs * g.x + bt.x;
    o.y = (v.y - mu) * rs * g.y + bt.y;
    o.z = (v.z - mu) * rs * g.z + bt.z;
    o.w = (v.w - mu) * rs * g.w + bt.w;
    ((float4*)(out + (size_t)row * ND))[tid] = o;
}

// ---------------------------------------------------------------------------
extern "C" void kernel_launch(void* const* d_in, const int* in_sizes, int n_in,
                              void* d_out, int out_size, void* d_ws, size_t ws_size,
                              hipStream_t stream)
{
    const float* x     = (const float*)d_in[0];
    const float* Wq    = (const float*)d_in[1];
    const float* Wk    = (const float*)d_in[2];
    const float* Wv    = (const float*)d_in[3];
    const float* Wo    = (const float*)d_in[4];
    const float* bo    = (const float*)d_in[5];
    const float* alpha = (const float*)d_in[6];
    const float* temp  = (const float*)d_in[7];
    const float* gamma = (const float*)d_in[8];
    const float* beta  = (const float*)d_in[9];

    char* ws = (char*)d_ws;
    u16* xb   = (u16*)(ws);                         // 33,554,432 B
    float* Part = (float*)(ws);                     // aliases xb (dead after gemm1)
    u16* wb   = (u16*)(ws + 33554432);              //  8,388,608 B
    u16* qkv  = (u16*)(ws + 41943040);              // 100,663,296 B
    u16* Mb   = (u16*)(ws + 142606336);             //  8,388,608 B
    float* y  = (float*)(ws + 150994944);           // 67,108,864 B  (total 208 MB)
    float* out = (float*)d_out;

    prep_cast<<<dim3(4096), dim3(256), 0, stream>>>(x, Wq, Wk, Wv, Wo, xb, wb);

    // QKV: [16384 x 3072] = x_bf16 @ [Wq;Wk;Wv]^T   (256x128 tiles)
    gemm_bt<0><<<dim3(24, 64), dim3(256), 0, stream>>>(
        xb, 1024, wb, 1024, (void*)qkv, 3072, 1024,
        nullptr, nullptr, 1 << 30, (size_t)0);

    // stage2 split: partials across 1024 blocks, then solve on 64 blocks
    stage2a_kernel<<<dim3(64, 16), dim3(256), 0, stream>>>(qkv, Part);
    stage2b_kernel<<<dim3(64), dim3(256), 0, stream>>>(Part, wb, alpha, temp, Mb);

    // y = q @ M_b^T + bo + x   (per-batch weights; 256 rows never straddle batch)
    gemm_bt<1><<<dim3(8, 64), dim3(256), 0, stream>>>(
        qkv, 3072, Mb, 1024, (void*)y, 1024, 1024,
        bo, x, 4096, (size_t)(1024 * 1024));

    ln_kernel<<<dim3(16384), dim3(256), 0, stream>>>(y, gamma, beta, out);
}